// Round 1
// baseline (14213.478 us; speedup 1.0000x reference)
//
#include <hip/hip_runtime.h>
#include <stdint.h>

// Problem constants
#define BB 512
#define TT 82
#define DD 129
#define DPAD 160
#define HH 1024
#define G4 4096
#define NOUT 128
#define NSTEPS 100

typedef unsigned short u16;
typedef __attribute__((ext_vector_type(8))) __bf16 bf16x8;
typedef __attribute__((ext_vector_type(8))) short short8;
typedef __attribute__((ext_vector_type(4))) float f32x4;
typedef __attribute__((ext_vector_type(4))) unsigned short u16x4;

__device__ __forceinline__ u16 f2bf(float f) {
  uint32_t u = __builtin_bit_cast(uint32_t, f);
  u += 0x7fffu + ((u >> 16) & 1u);   // round to nearest even
  return (u16)(u >> 16);
}
__device__ __forceinline__ float bf2f(u16 h) {
  uint32_t u = ((uint32_t)h) << 16;
  return __builtin_bit_cast(float, u);
}
__device__ __forceinline__ float sigm(float x) { return 1.f / (1.f + __expf(-x)); }
__device__ __forceinline__ float tanhfast(float x) {
  // overflow-safe: e = exp(2|x|) -> inf gives t -> 1
  float ax = fabsf(x);
  float e = __expf(2.f * ax);
  float t = 1.f - 2.f / (e + 1.f);
  return copysignf(t, x);
}

__device__ __forceinline__ void glds16(const void* g, void* l) {
  __builtin_amdgcn_global_load_lds((const __attribute__((address_space(1))) void*)g,
                                   (__attribute__((address_space(3))) void*)l, 16, 0, 0);
}

// G[512, N] = A0[512,K0] @ W0[N,K0]^T (+ A1[512,K1] @ W1[N,K1]^T) + b1 + b2
// MODE 0: bf16 out -> Gout[512,4096]
// MODE 1: fp32 out -> Fout (row stride fstride) AND bf16 copy -> FoutB[512,128]
// Tile: BM=64 (blockIdx.y), BN=128 (blockIdx.x), BK=32. 256 threads = 4 waves (2x2),
// wave tile 32x64 = 2x4 MFMA 16x16x32_bf16 tiles. All K multiples of 32, M=512, N%128==0.
template <int MODE>
__global__ __launch_bounds__(256) void gemm_step(
    const u16* __restrict__ A0, int K0, const u16* __restrict__ W0,
    const u16* __restrict__ A1, int K1, const u16* __restrict__ W1,
    const float* __restrict__ b1, const float* __restrict__ b2,
    u16* __restrict__ Gout,
    float* __restrict__ Fout, int fstride, u16* __restrict__ FoutB)
{
  __shared__ __align__(16) u16 At[64 * 32];    // 4 KB
  __shared__ __align__(16) u16 Bt[128 * 32];   // 8 KB
  const int tid = threadIdx.x;
  const int lane = tid & 63;
  const int w = tid >> 6;
  const int m0 = blockIdx.y * 64;
  const int n0 = blockIdx.x * 128;
  const int waveM = w >> 1;
  const int waveN = w & 1;
  const int srow = tid >> 2;          // staging row 0..63 (4 x 16B chunks per 64B row)
  const int sk = (tid & 3) * 8;       // staging k offset (elements)

  f32x4 acc[2][4] = {};

  #pragma unroll
  for (int s = 0; s < 2; ++s) {
    const u16* A = s ? A1 : A0;
    const u16* W = s ? W1 : W0;
    const int K = s ? K1 : K0;
    if (A == nullptr || K == 0) continue;
    for (int kb = 0; kb < K; kb += 32) {
      // A tile: 64x32 bf16, wave-uniform LDS base + lane*16
      glds16(A + (size_t)(m0 + srow) * K + kb + sk, At + w * 512);
      // B tile: 128x32 bf16, two chunks per thread
      glds16(W + (size_t)(n0 + srow) * K + kb + sk, Bt + w * 512);
      glds16(W + (size_t)(n0 + 64 + srow) * K + kb + sk, Bt + 2048 + w * 512);
      __syncthreads();
      const int ar = lane & 15;
      const int kq = (lane >> 4) * 8;
      bf16x8 af[2], bfr[4];
      #pragma unroll
      for (int ti = 0; ti < 2; ++ti) {
        short8 raw = *(const short8*)&At[(waveM * 32 + ti * 16 + ar) * 32 + kq];
        af[ti] = __builtin_bit_cast(bf16x8, raw);
      }
      #pragma unroll
      for (int tj = 0; tj < 4; ++tj) {
        short8 raw = *(const short8*)&Bt[(waveN * 64 + tj * 16 + ar) * 32 + kq];
        bfr[tj] = __builtin_bit_cast(bf16x8, raw);
      }
      #pragma unroll
      for (int ti = 0; ti < 2; ++ti)
        #pragma unroll
        for (int tj = 0; tj < 4; ++tj)
          acc[ti][tj] = __builtin_amdgcn_mfma_f32_16x16x32_bf16(af[ti], bfr[tj], acc[ti][tj], 0, 0, 0);
      __syncthreads();
    }
  }

  // epilogue: C/D mapping col = lane&15, row = (lane>>4)*4 + r  [verified m89/m91]
  #pragma unroll
  for (int ti = 0; ti < 2; ++ti) {
    const int mb = m0 + waveM * 32 + ti * 16 + ((lane >> 4) << 2);
    #pragma unroll
    for (int tj = 0; tj < 4; ++tj) {
      const int n = n0 + waveN * 64 + tj * 16 + (lane & 15);
      float bias = 0.f;
      if (b1) bias += b1[n];
      if (b2) bias += b2[n];
      #pragma unroll
      for (int r = 0; r < 4; ++r) {
        const float v = acc[ti][tj][r] + bias;
        const int m = mb + r;
        if (MODE == 0) {
          Gout[(size_t)m * G4 + n] = f2bf(v);
        } else {
          Fout[(size_t)m * fstride + n] = v;
          FoutB[m * NOUT + n] = f2bf(v);
        }
      }
    }
  }
}

// Gate elementwise: G[512,4096] bf16 preactivations (i|f|g|o), c fp32, h bf16.
// t >= 0: encoder (mask: update only if t < lengths[b]); t < 0: decoder (always).
__global__ __launch_bounds__(256) void gate_step(
    const u16* __restrict__ G, float* __restrict__ c, u16* __restrict__ hb,
    const int* __restrict__ lengths, int t)
{
  const int v = blockIdx.x * 256 + threadIdx.x;   // 131072 threads, 4 elems each
  const int b = v >> 8;
  const int j = (v & 255) * 4;
  const size_t gbase = (size_t)b * G4 + j;
  const size_t ci = (size_t)b * HH + j;
  f32x4 cv = *(const f32x4*)(c + ci);
  const bool upd = (t < 0) || (t < lengths[b]);
  f32x4 cno;
  u16x4 hno;
  #pragma unroll
  for (int k = 0; k < 4; ++k) {
    float gi = bf2f(G[gbase + k]);
    float gf = bf2f(G[gbase + 1024 + k]);
    float gg = bf2f(G[gbase + 2048 + k]);
    float go = bf2f(G[gbase + 3072 + k]);
    float cn = sigm(gf) * cv[k] + sigm(gi) * tanhfast(gg);
    float hn = sigm(go) * tanhfast(cn);
    cno[k] = cn;
    hno[k] = f2bf(hn);
  }
  if (upd) {
    *(f32x4*)(c + ci) = cno;
    *(u16x4*)(hb + ci) = hno;
  }
}

// fp32 [R,C] -> bf16 [R,Cp] with zero pad
__global__ void conv_w(const float* __restrict__ w, u16* __restrict__ wb,
                       int C, int Cp, int total)
{
  int idx = blockIdx.x * 256 + threadIdx.x;
  if (idx >= total) return;
  int cc = idx % Cp;
  int r = idx / Cp;
  wb[idx] = f2bf(cc < C ? w[(size_t)r * C + cc] : 0.f);
}

// x [B,T,129] fp32 -> xb [T,B,160] bf16 (zero-padded)
__global__ void conv_x(const float* __restrict__ x, u16* __restrict__ xb)
{
  int idx = blockIdx.x * 256 + threadIdx.x;
  if (idx >= TT * BB * DPAD) return;
  int k = idx % DPAD;
  int tb = idx / DPAD;
  int b = tb & (BB - 1);
  int t = tb / BB;
  xb[idx] = f2bf(k < DD ? x[((size_t)b * TT + t) * DD + k] : 0.f);
}

extern "C" void kernel_launch(void* const* d_in, const int* in_sizes, int n_in,
                              void* d_out, int out_size, void* d_ws, size_t ws_size,
                              hipStream_t stream) {
  (void)in_sizes; (void)n_in; (void)out_size; (void)ws_size;
  const float* x     = (const float*)d_in[0];
  const int*   lens  = (const int*)d_in[1];
  const float* eWih0 = (const float*)d_in[2];
  const float* eWhh0 = (const float*)d_in[3];
  const float* ebih0 = (const float*)d_in[4];
  const float* ebhh0 = (const float*)d_in[5];
  const float* eWih1 = (const float*)d_in[6];
  const float* eWhh1 = (const float*)d_in[7];
  const float* ebih1 = (const float*)d_in[8];
  const float* ebhh1 = (const float*)d_in[9];
  const float* dWih0 = (const float*)d_in[10];
  const float* dWhh0 = (const float*)d_in[11];
  const float* dbih0 = (const float*)d_in[12];
  const float* dbhh0 = (const float*)d_in[13];
  const float* dWih1 = (const float*)d_in[14];
  const float* dWhh1 = (const float*)d_in[15];
  const float* dbih1 = (const float*)d_in[16];
  const float* dbhh1 = (const float*)d_in[17];
  const float* fcW   = (const float*)d_in[18];
  const float* fcb   = (const float*)d_in[19];
  float* out = (float*)d_out;

  // carve workspace (~78 MB), 256B aligned
  char* p = (char*)d_ws;
  auto carve = [&](size_t bytes) -> void* {
    void* q = (void*)p;
    p += (bytes + 255) & ~(size_t)255;
    return q;
  };
  u16* eWih0b = (u16*)carve((size_t)G4 * DPAD * 2);
  u16* eWhh0b = (u16*)carve((size_t)G4 * HH * 2);
  u16* eWih1b = (u16*)carve((size_t)G4 * HH * 2);
  u16* eWhh1b = (u16*)carve((size_t)G4 * HH * 2);
  u16* dWih0b = (u16*)carve((size_t)G4 * NOUT * 2);
  u16* dWhh0b = (u16*)carve((size_t)G4 * HH * 2);
  u16* dWih1b = (u16*)carve((size_t)G4 * HH * 2);
  u16* dWhh1b = (u16*)carve((size_t)G4 * HH * 2);
  u16* fcWb   = (u16*)carve((size_t)NOUT * HH * 2);
  u16* xb     = (u16*)carve((size_t)TT * BB * DPAD * 2);
  u16* h0b    = (u16*)carve((size_t)BB * HH * 2);
  u16* h1b    = (u16*)carve((size_t)BB * HH * 2);
  u16* outb   = (u16*)carve((size_t)BB * NOUT * 2);
  float* c0   = (float*)carve((size_t)BB * HH * 4);
  float* c1   = (float*)carve((size_t)BB * HH * 4);
  u16* G      = (u16*)carve((size_t)BB * G4 * 2);

  // weight + input conversion (every call: inputs restored, ws re-poisoned)
  auto cw = [&](const float* src, u16* dst, int C, int Cp, int R) {
    int total = R * Cp;
    conv_w<<<dim3((total + 255) / 256), dim3(256), 0, stream>>>(src, dst, C, Cp, total);
  };
  cw(eWih0, eWih0b, DD, DPAD, G4);
  cw(eWhh0, eWhh0b, HH, HH, G4);
  cw(eWih1, eWih1b, HH, HH, G4);
  cw(eWhh1, eWhh1b, HH, HH, G4);
  cw(dWih0, dWih0b, NOUT, NOUT, G4);
  cw(dWhh0, dWhh0b, HH, HH, G4);
  cw(dWih1, dWih1b, HH, HH, G4);
  cw(dWhh1, dWhh1b, HH, HH, G4);
  cw(fcW, fcWb, HH, HH, NOUT);
  conv_x<<<dim3((TT * BB * DPAD + 255) / 256), dim3(256), 0, stream>>>(x, xb);

  hipMemsetAsync(h0b, 0, (size_t)BB * HH * 2, stream);
  hipMemsetAsync(h1b, 0, (size_t)BB * HH * 2, stream);
  hipMemsetAsync(c0, 0, (size_t)BB * HH * 4, stream);
  hipMemsetAsync(c1, 0, (size_t)BB * HH * 4, stream);

  const dim3 gg(G4 / 128, BB / 64);   // (32, 8)
  const dim3 gfc(NOUT / 128, BB / 64); // (1, 8)

  // encoder: 82 masked steps
  for (int t = 0; t < TT; ++t) {
    gemm_step<0><<<gg, 256, 0, stream>>>(
        h0b, HH, eWhh0b, xb + (size_t)t * BB * DPAD, DPAD, eWih0b,
        ebih0, ebhh0, G, (float*)nullptr, 0, (u16*)nullptr);
    gate_step<<<512, 256, 0, stream>>>(G, c0, h0b, lens, t);
    gemm_step<0><<<gg, 256, 0, stream>>>(
        h1b, HH, eWhh1b, h0b, HH, eWih1b,
        ebih1, ebhh1, G, (float*)nullptr, 0, (u16*)nullptr);
    gate_step<<<512, 256, 0, stream>>>(G, c1, h1b, lens, t);
  }

  // decoder: 100 autoregressive steps (input 0 at s=0 -> skip that K-source)
  for (int s = 0; s < NSTEPS; ++s) {
    gemm_step<0><<<gg, 256, 0, stream>>>(
        h0b, HH, dWhh0b,
        (s == 0 ? (const u16*)nullptr : (const u16*)outb), (s == 0 ? 0 : NOUT), dWih0b,
        dbih0, dbhh0, G, (float*)nullptr, 0, (u16*)nullptr);
    gate_step<<<512, 256, 0, stream>>>(G, c0, h0b, lens, -1);
    gemm_step<0><<<gg, 256, 0, stream>>>(
        h1b, HH, dWhh1b, h0b, HH, dWih1b,
        dbih1, dbhh1, G, (float*)nullptr, 0, (u16*)nullptr);
    gate_step<<<512, 256, 0, stream>>>(G, c1, h1b, lens, -1);
    gemm_step<1><<<gfc, 256, 0, stream>>>(
        h1b, HH, fcWb, (const u16*)nullptr, 0, (const u16*)nullptr,
        fcb, (const float*)nullptr, (u16*)nullptr,
        out + (size_t)s * NOUT, NSTEPS * NOUT, outb);
  }
}

// Round 2
// 11039.184 us; speedup vs baseline: 1.2875x; 1.2875x over previous
//
#include <hip/hip_runtime.h>
#include <stdint.h>

// Problem constants
#define BB 512
#define TT 82
#define DD 129
#define DXP 192      // x K padded to multiple of 64
#define HH 1024
#define G4 4096
#define NOUT 128
#define NSTEPS 100

typedef unsigned short u16;
typedef __attribute__((ext_vector_type(8))) __bf16 bf16x8;
typedef __attribute__((ext_vector_type(8))) short short8;
typedef __attribute__((ext_vector_type(4))) float f32x4;

__device__ __forceinline__ u16 f2bf(float f) {
  uint32_t u = __builtin_bit_cast(uint32_t, f);
  u += 0x7fffu + ((u >> 16) & 1u);   // round to nearest even
  return (u16)(u >> 16);
}
__device__ __forceinline__ float bf2f(u16 h) {
  uint32_t u = ((uint32_t)h) << 16;
  return __builtin_bit_cast(float, u);
}
__device__ __forceinline__ float sigm(float x) { return 1.f / (1.f + __expf(-x)); }
__device__ __forceinline__ float tanhfast(float x) {
  float ax = fabsf(x);
  float e = __expf(2.f * ax);
  float t = 1.f - 2.f / (e + 1.f);
  return copysignf(t, x);
}
__device__ __forceinline__ void glds16(const void* g, void* l) {
  __builtin_amdgcn_global_load_lds((const __attribute__((address_space(1))) void*)g,
                                   (__attribute__((address_space(3))) void*)l, 16, 0, 0);
}

// Fused step GEMM.
// G[M, N] = A0[M,K0] @ W0[N,K0]^T + A1[M,K1] @ W1[N,K1]^T  (K1 may be 0)
// FUSE=1: N=4096, W rows gate-permuted (per 64-row group: 16 units x 4 gates:
//         perm row n -> orig gate=(n>>4)&3, unit=(n>>6)*16+(n&15)).
//         Epilogue applies LSTM cell: c (fp32, in-place), h (bf16) read from
//         A0 (= h_prev) on masked rows, written to hnext. Mask: t>=0 encoder.
// FUSE=0: N=128 (fc). fout[m*12800 + n] = v (fp32), foutb[m*128+n] = bf16(v).
// Tile: BM=64 (blockIdx.y), BN=128 (blockIdx.x), BK=64. 256 thr = 4 waves 2x2,
// wave tile 32x64. LDS XOR-swizzled: slot(r,c16) holds global chunk c16^(r&7).
// Double-buffered; prefetch issued after barrier, covered by compute.
template <int FUSE>
__global__ __launch_bounds__(256) void step_gemm(
    const u16* __restrict__ A0, int K0, const u16* __restrict__ W0,
    const u16* __restrict__ A1, int K1, const u16* __restrict__ W1,
    const float* __restrict__ bias,
    float* __restrict__ cst, u16* __restrict__ hnext,
    const int* __restrict__ lengths, int t,
    float* __restrict__ fout, u16* __restrict__ foutb)
{
  __shared__ __align__(16) u16 At[2][64 * 64];     // 8 KB x2
  __shared__ __align__(16) u16 Bt[2][128 * 64];    // 16 KB x2
  const int tid = threadIdx.x;
  const int lane = tid & 63;
  const int w = tid >> 6;
  const int waveM = w >> 1;
  const int waveN = w & 1;
  const int m0 = blockIdx.y * 64;
  const int n0 = blockIdx.x * 128;

  const int nIter0 = K0 >> 6;
  const int nIterT = nIter0 + (K1 >> 6);

  auto stage = [&](int i, int buf) {
    const u16* A; const u16* W; int K; int kb;
    if (i < nIter0) { A = A0; W = W0; K = K0; kb = i << 6; }
    else            { A = A1; W = W1; K = K1; kb = (i - nIter0) << 6; }
    // A: 64 rows x 8 chunks16 = 512 slots, 2/thread
    #pragma unroll
    for (int j = 0; j < 2; ++j) {
      int slot = tid + j * 256;
      int r = slot >> 3, c = slot & 7;
      int g = c ^ (r & 7);
      glds16(A + (size_t)(m0 + r) * K + kb + g * 8,
             &At[buf][(j * 256 + w * 64) * 8]);
    }
    // B: 128 rows x 8 chunks16 = 1024 slots, 4/thread
    #pragma unroll
    for (int j = 0; j < 4; ++j) {
      int slot = tid + j * 256;
      int r = slot >> 3, c = slot & 7;
      int g = c ^ (r & 7);
      glds16(W + (size_t)(n0 + r) * K + kb + g * 8,
             &Bt[buf][(j * 256 + w * 64) * 8]);
    }
  };

  f32x4 acc[2][4] = {};

  stage(0, 0);
  for (int i = 0; i < nIterT; ++i) {
    __syncthreads();                       // drains stage(i); prefetch below
    if (i + 1 < nIterT) stage(i + 1, (i + 1) & 1);
    const int buf = i & 1;
    #pragma unroll
    for (int kc = 0; kc < 2; ++kc) {
      bf16x8 af[2], bfr[4];
      const int gch = kc * 4 + (lane >> 4);
      #pragma unroll
      for (int ti = 0; ti < 2; ++ti) {
        int r = waveM * 32 + ti * 16 + (lane & 15);
        int c = gch ^ (r & 7);
        af[ti] = __builtin_bit_cast(bf16x8, *(const short8*)&At[buf][(r * 8 + c) * 8]);
      }
      #pragma unroll
      for (int tj = 0; tj < 4; ++tj) {
        int r = waveN * 64 + tj * 16 + (lane & 15);
        int c = gch ^ (r & 7);
        bfr[tj] = __builtin_bit_cast(bf16x8, *(const short8*)&Bt[buf][(r * 8 + c) * 8]);
      }
      #pragma unroll
      for (int ti = 0; ti < 2; ++ti)
        #pragma unroll
        for (int tj = 0; tj < 4; ++tj)
          acc[ti][tj] = __builtin_amdgcn_mfma_f32_16x16x32_bf16(af[ti], bfr[tj], acc[ti][tj], 0, 0, 0);
    }
  }
  __syncthreads();

  const int col = lane & 15;
  const int rq = (lane >> 4) << 2;

  if (FUSE) {
    // wave covers one 64-row gate group: units j0..j0+15, gates = tj
    const int j = (blockIdx.x * 2 + waveN) * 16 + col;
    float bv[4];
    #pragma unroll
    for (int tj = 0; tj < 4; ++tj) bv[tj] = bias[n0 + waveN * 64 + tj * 16 + col];
    #pragma unroll
    for (int ti = 0; ti < 2; ++ti) {
      const int mb = m0 + waveM * 32 + ti * 16 + rq;
      #pragma unroll
      for (int r = 0; r < 4; ++r) {
        const int m = mb + r;
        const size_t idx = ((size_t)m << 10) + j;
        const bool upd = (t < 0) || (t < lengths[m]);
        if (upd) {
          float cv = cst[idx];
          float gi = acc[ti][0][r] + bv[0];
          float gf = acc[ti][1][r] + bv[1];
          float gg = acc[ti][2][r] + bv[2];
          float go = acc[ti][3][r] + bv[3];
          float cn = sigm(gf) * cv + sigm(gi) * tanhfast(gg);
          float hn = sigm(go) * tanhfast(cn);
          cst[idx] = cn;
          hnext[idx] = f2bf(hn);
        } else {
          hnext[idx] = A0[idx];   // carry h through (c untouched)
        }
      }
    }
  } else {
    #pragma unroll
    for (int ti = 0; ti < 2; ++ti) {
      const int mb = m0 + waveM * 32 + ti * 16 + rq;
      #pragma unroll
      for (int tj = 0; tj < 4; ++tj) {
        const int n = n0 + waveN * 64 + tj * 16 + col;
        const float bv = bias[n];
        #pragma unroll
        for (int r = 0; r < 4; ++r) {
          const int m = mb + r;
          const float v = acc[ti][tj][r] + bv;
          fout[(size_t)m * (NSTEPS * NOUT) + n] = v;
          foutb[m * NOUT + n] = f2bf(v);
        }
      }
    }
  }
}

// fp32 [R,C] -> bf16 [R,Cp], optional gate-row permutation (R=4096)
__global__ void conv_wp(const float* __restrict__ w, u16* __restrict__ wb,
                        int C, int Cp, int R, int perm, int total)
{
  int idx = blockIdx.x * 256 + threadIdx.x;
  if (idx >= total) return;
  int cc = idx % Cp;
  int n = idx / Cp;
  int orig = perm ? (((n >> 4) & 3) * (R >> 2) + (n >> 6) * 16 + (n & 15)) : n;
  wb[idx] = f2bf(cc < C ? w[(size_t)orig * C + cc] : 0.f);
}

// permuted combined bias [4096]
__global__ void conv_b(const float* __restrict__ b1, const float* __restrict__ b2,
                       float* __restrict__ bp)
{
  int n = blockIdx.x * 256 + threadIdx.x;
  if (n >= G4) return;
  int orig = ((n >> 4) & 3) * HH + (n >> 6) * 16 + (n & 15);
  bp[n] = b1[orig] + b2[orig];
}

// x [B,T,129] fp32 -> xb [T,B,192] bf16 zero-padded
__global__ void conv_x(const float* __restrict__ x, u16* __restrict__ xb)
{
  int idx = blockIdx.x * 256 + threadIdx.x;
  if (idx >= TT * BB * DXP) return;
  int k = idx % DXP;
  int tb = idx / DXP;
  int b = tb & (BB - 1);
  int t = tb / BB;
  xb[idx] = f2bf(k < DD ? x[((size_t)b * TT + t) * DD + k] : 0.f);
}

extern "C" void kernel_launch(void* const* d_in, const int* in_sizes, int n_in,
                              void* d_out, int out_size, void* d_ws, size_t ws_size,
                              hipStream_t stream) {
  (void)in_sizes; (void)n_in; (void)out_size; (void)ws_size;
  const float* x     = (const float*)d_in[0];
  const int*   lens  = (const int*)d_in[1];
  const float* eWih0 = (const float*)d_in[2];
  const float* eWhh0 = (const float*)d_in[3];
  const float* ebih0 = (const float*)d_in[4];
  const float* ebhh0 = (const float*)d_in[5];
  const float* eWih1 = (const float*)d_in[6];
  const float* eWhh1 = (const float*)d_in[7];
  const float* ebih1 = (const float*)d_in[8];
  const float* ebhh1 = (const float*)d_in[9];
  const float* dWih0 = (const float*)d_in[10];
  const float* dWhh0 = (const float*)d_in[11];
  const float* dbih0 = (const float*)d_in[12];
  const float* dbhh0 = (const float*)d_in[13];
  const float* dWih1 = (const float*)d_in[14];
  const float* dWhh1 = (const float*)d_in[15];
  const float* dbih1 = (const float*)d_in[16];
  const float* dbhh1 = (const float*)d_in[17];
  const float* fcW   = (const float*)d_in[18];
  const float* fcb   = (const float*)d_in[19];
  float* out = (float*)d_out;

  char* p = (char*)d_ws;
  auto carve = [&](size_t bytes) -> void* {
    void* q = (void*)p;
    p += (bytes + 255) & ~(size_t)255;
    return q;
  };
  u16* eWih0b = (u16*)carve((size_t)G4 * DXP * 2);
  u16* eWhh0b = (u16*)carve((size_t)G4 * HH * 2);
  u16* eWih1b = (u16*)carve((size_t)G4 * HH * 2);
  u16* eWhh1b = (u16*)carve((size_t)G4 * HH * 2);
  u16* dWih0b = (u16*)carve((size_t)G4 * NOUT * 2);
  u16* dWhh0b = (u16*)carve((size_t)G4 * HH * 2);
  u16* dWih1b = (u16*)carve((size_t)G4 * HH * 2);
  u16* dWhh1b = (u16*)carve((size_t)G4 * HH * 2);
  u16* fcWb   = (u16*)carve((size_t)NOUT * HH * 2);
  float* be0  = (float*)carve((size_t)G4 * 4);
  float* be1  = (float*)carve((size_t)G4 * 4);
  float* bd0  = (float*)carve((size_t)G4 * 4);
  float* bd1  = (float*)carve((size_t)G4 * 4);
  u16* xb     = (u16*)carve((size_t)TT * BB * DXP * 2);
  u16* h0p[2] = { (u16*)carve((size_t)BB * HH * 2), (u16*)carve((size_t)BB * HH * 2) };
  u16* h1p[2] = { (u16*)carve((size_t)BB * HH * 2), (u16*)carve((size_t)BB * HH * 2) };
  u16* outb   = (u16*)carve((size_t)BB * NOUT * 2);
  float* c0   = (float*)carve((size_t)BB * HH * 4);
  float* c1   = (float*)carve((size_t)BB * HH * 4);

  auto cw = [&](const float* src, u16* dst, int C, int Cp, int R, int perm) {
    int total = R * Cp;
    conv_wp<<<dim3((total + 255) / 256), dim3(256), 0, stream>>>(src, dst, C, Cp, R, perm, total);
  };
  cw(eWih0, eWih0b, DD, DXP, G4, 1);
  cw(eWhh0, eWhh0b, HH, HH, G4, 1);
  cw(eWih1, eWih1b, HH, HH, G4, 1);
  cw(eWhh1, eWhh1b, HH, HH, G4, 1);
  cw(dWih0, dWih0b, NOUT, NOUT, G4, 1);
  cw(dWhh0, dWhh0b, HH, HH, G4, 1);
  cw(dWih1, dWih1b, HH, HH, G4, 1);
  cw(dWhh1, dWhh1b, HH, HH, G4, 1);
  cw(fcW, fcWb, HH, HH, NOUT, 0);
  conv_b<<<dim3(16), dim3(256), 0, stream>>>(ebih0, ebhh0, be0);
  conv_b<<<dim3(16), dim3(256), 0, stream>>>(ebih1, ebhh1, be1);
  conv_b<<<dim3(16), dim3(256), 0, stream>>>(dbih0, dbhh0, bd0);
  conv_b<<<dim3(16), dim3(256), 0, stream>>>(dbih1, dbhh1, bd1);
  conv_x<<<dim3((TT * BB * DXP + 255) / 256), dim3(256), 0, stream>>>(x, xb);

  hipMemsetAsync(h0p[0], 0, (size_t)BB * HH * 2, stream);
  hipMemsetAsync(h1p[0], 0, (size_t)BB * HH * 2, stream);
  hipMemsetAsync(c0, 0, (size_t)BB * HH * 4, stream);
  hipMemsetAsync(c1, 0, (size_t)BB * HH * 4, stream);

  const dim3 gg(G4 / 128, BB / 64);    // (32, 8)
  const dim3 gfc(1, BB / 64);          // (1, 8)

  // encoder: global step g = t; h_prev = buf[g&1], h_next = buf[(g+1)&1]
  for (int t = 0; t < TT; ++t) {
    const int pr = t & 1, nx = (t + 1) & 1;
    step_gemm<1><<<gg, 256, 0, stream>>>(
        h0p[pr], HH, eWhh0b, xb + (size_t)t * BB * DXP, DXP, eWih0b,
        be0, c0, h0p[nx], lens, t, (float*)nullptr, (u16*)nullptr);
    step_gemm<1><<<gg, 256, 0, stream>>>(
        h1p[pr], HH, eWhh1b, h0p[nx], HH, eWih1b,
        be1, c1, h1p[nx], lens, t, (float*)nullptr, (u16*)nullptr);
  }

  // decoder: global step g = TT + s
  for (int s = 0; s < NSTEPS; ++s) {
    const int g = TT + s;
    const int pr = g & 1, nx = (g + 1) & 1;
    step_gemm<1><<<gg, 256, 0, stream>>>(
        h0p[pr], HH, dWhh0b,
        (s == 0 ? (const u16*)nullptr : (const u16*)outb), (s == 0 ? 0 : NOUT), dWih0b,
        bd0, c0, h0p[nx], lens, -1, (float*)nullptr, (u16*)nullptr);
    step_gemm<1><<<gg, 256, 0, stream>>>(
        h1p[pr], HH, dWhh1b, h0p[nx], HH, dWih1b,
        bd1, c1, h1p[nx], lens, -1, (float*)nullptr, (u16*)nullptr);
    step_gemm<0><<<gfc, 256, 0, stream>>>(
        h1p[nx], HH, fcWb, (const u16*)nullptr, 0, (const u16*)nullptr,
        fcb, (float*)nullptr, (u16*)nullptr, (const int*)nullptr, -1,
        out + (size_t)s * NOUT, outb);
  }
}